// Round 1
// baseline (152.031 us; speedup 1.0000x reference)
//
#include <hip/hip_runtime.h>

#define B_N 4096
#define D_K 256
#define TILE 64
#define NT (B_N / TILE)     // 64 tiles per dim
#define BK 32
#define NTHREADS 256

// ---------------------------------------------------------------------------
// prep: per-row squared norm + packed label (labels in [0,8), L=3 -> 9 bits)
// one wave (64 lanes) per row; lane reads one float4 (256 floats / row)
// ---------------------------------------------------------------------------
__global__ __launch_bounds__(64) void prep_kernel(const float* __restrict__ F,
                                                  const int* __restrict__ labels,
                                                  float* __restrict__ sq,
                                                  int* __restrict__ plab) {
    int row  = blockIdx.x;
    int lane = threadIdx.x;
    const float4* fp = reinterpret_cast<const float4*>(F + (size_t)row * D_K);
    float4 v = fp[lane];
    float s = v.x * v.x + v.y * v.y + v.z * v.z + v.w * v.w;
#pragma unroll
    for (int off = 32; off > 0; off >>= 1) s += __shfl_down(s, off);
    if (lane == 0) {
        sq[row] = s;
        const int* lp = labels + (size_t)row * 3;
        plab[row] = lp[0] | (lp[1] << 3) | (lp[2] << 6);
    }
}

// ---------------------------------------------------------------------------
// pair: upper-triangular tile grid of 64x64 gram tiles.
// 16x16 threads, 4x4 accumulators/thread, BK=32 LDS staging (+1 pad).
// Epilogue: d2 = sq_i + sq_j - 2*g, safe sqrt, contrastive term, j>i mask,
// block reduction, one atomicAdd per block (scaled by 1/B).
// ---------------------------------------------------------------------------
__global__ __launch_bounds__(NTHREADS) void pair_kernel(const float* __restrict__ F,
                                                        const float* __restrict__ sq,
                                                        const int* __restrict__ plab,
                                                        float* __restrict__ out) {
    // triangular decode: tiles (bi, bj) with bi <= bj
    int idx = blockIdx.x;
    int bi = 0;
    while (idx >= NT - bi) { idx -= NT - bi; ++bi; }
    int bj = bi + idx;

    __shared__ float As[TILE][BK + 1];
    __shared__ float Bs[TILE][BK + 1];
    __shared__ float red[NTHREADS / 64];

    const int t  = threadIdx.x;
    const int tx = t & 15;        // 0..15  -> j sub-tile
    const int ty = t >> 4;        // 0..15  -> i sub-tile

    const int i0 = bi * TILE;
    const int j0 = bj * TILE;

    float acc[4][4];
#pragma unroll
    for (int r = 0; r < 4; ++r)
#pragma unroll
        for (int c = 0; c < 4; ++c) acc[r][c] = 0.f;

    for (int k0 = 0; k0 < D_K; k0 += BK) {
        // stage A (rows i0..i0+63) and B (rows j0..j0+63), cols k0..k0+31
        // 64 rows x 8 float4 = 512 float4 per tile; 256 threads -> 2 iters
#pragma unroll
        for (int l = t; l < TILE * (BK / 4); l += NTHREADS) {
            int row = l >> 3;       // /8
            int c4  = l & 7;
            float4 va = *reinterpret_cast<const float4*>(F + (size_t)(i0 + row) * D_K + k0 + c4 * 4);
            float4 vb = *reinterpret_cast<const float4*>(F + (size_t)(j0 + row) * D_K + k0 + c4 * 4);
            As[row][c4 * 4 + 0] = va.x; As[row][c4 * 4 + 1] = va.y;
            As[row][c4 * 4 + 2] = va.z; As[row][c4 * 4 + 3] = va.w;
            Bs[row][c4 * 4 + 0] = vb.x; Bs[row][c4 * 4 + 1] = vb.y;
            Bs[row][c4 * 4 + 2] = vb.z; Bs[row][c4 * 4 + 3] = vb.w;
        }
        __syncthreads();

#pragma unroll 4
        for (int k = 0; k < BK; ++k) {
            float a[4], b[4];
#pragma unroll
            for (int r = 0; r < 4; ++r) a[r] = As[ty * 4 + r][k];
#pragma unroll
            for (int c = 0; c < 4; ++c) b[c] = Bs[tx * 4 + c][k];
#pragma unroll
            for (int r = 0; r < 4; ++r)
#pragma unroll
                for (int c = 0; c < 4; ++c) acc[r][c] = fmaf(a[r], b[c], acc[r][c]);
        }
        __syncthreads();
    }

    // epilogue
    const int ibase = i0 + ty * 4;
    const int jbase = j0 + tx * 4;
    float sqi[4], sqj[4];
    int   li[4],  lj[4];
#pragma unroll
    for (int r = 0; r < 4; ++r) { sqi[r] = sq[ibase + r]; li[r] = plab[ibase + r]; }
#pragma unroll
    for (int c = 0; c < 4; ++c) { sqj[c] = sq[jbase + c]; lj[c] = plab[jbase + c]; }

    float local = 0.f;
#pragma unroll
    for (int r = 0; r < 4; ++r) {
#pragma unroll
        for (int c = 0; c < 4; ++c) {
            int i = ibase + r, j = jbase + c;
            if (j > i) {
                float d2 = sqi[r] + sqj[c] - 2.f * acc[r][c];
                d2 = fmaxf(d2, 0.f);
                float dist = (d2 > 0.f) ? sqrtf(d2) : 0.f;
                float term = (li[r] == lj[c]) ? (0.5f * dist)
                                              : (0.5f * fmaxf(1.f - dist, 0.f));
                local += term;
            }
        }
    }

    // block reduce: wave shuffle, then cross-wave via LDS
#pragma unroll
    for (int off = 32; off > 0; off >>= 1) local += __shfl_down(local, off);
    int wave = t >> 6;
    if ((t & 63) == 0) red[wave] = local;
    __syncthreads();
    if (t == 0) {
        float s = 0.f;
#pragma unroll
        for (int w = 0; w < NTHREADS / 64; ++w) s += red[w];
        atomicAdd(out, s * (1.0f / B_N));
    }
}

extern "C" void kernel_launch(void* const* d_in, const int* in_sizes, int n_in,
                              void* d_out, int out_size, void* d_ws, size_t ws_size,
                              hipStream_t stream) {
    const float* F      = (const float*)d_in[0];
    const int*   labels = (const int*)d_in[1];
    float* out = (float*)d_out;

    float* sq   = (float*)d_ws;                              // 4096 floats
    int*   plab = (int*)((char*)d_ws + B_N * sizeof(float)); // 4096 ints

    hipMemsetAsync(out, 0, sizeof(float), stream);
    prep_kernel<<<B_N, 64, 0, stream>>>(F, labels, sq, plab);
    pair_kernel<<<NT * (NT + 1) / 2, NTHREADS, 0, stream>>>(F, sq, plab, out);
}

// Round 2
// 109.210 us; speedup vs baseline: 1.3921x; 1.3921x over previous
//
#include <hip/hip_runtime.h>

#define B_N 4096
#define D_K 256
#define TILE 64
#define NT (B_N / TILE)     // 64 tiles per dim -> 2080 triangular blocks

typedef __bf16 bf16x8 __attribute__((ext_vector_type(8)));
typedef float  floatx4 __attribute__((ext_vector_type(4)));

// exact RNE float->bf16 (inputs are finite, NaN path not needed)
__device__ inline unsigned short f2bf(float f) {
    unsigned int u = __float_as_uint(f);
    unsigned int r = (u + 0x7FFFu + ((u >> 16) & 1u)) >> 16;
    return (unsigned short)r;
}

// ---------------------------------------------------------------------------
// prep: per-row squared norm (fp32, exact), packed label, bf16 copy of F.
// one wave per row; lane holds one float4 (256 floats / 64 lanes).
// ---------------------------------------------------------------------------
__global__ __launch_bounds__(256) void prep_kernel(const float* __restrict__ F,
                                                   const int* __restrict__ labels,
                                                   float* __restrict__ sq,
                                                   int* __restrict__ plab,
                                                   unsigned short* __restrict__ Fb) {
    int row  = blockIdx.x * 4 + (threadIdx.x >> 6);
    int lane = threadIdx.x & 63;
    const float4* fp = reinterpret_cast<const float4*>(F + (size_t)row * D_K);
    float4 v = fp[lane];
    // bf16 copy (8 contiguous bytes per lane, coalesced)
    ushort4 b;
    b.x = f2bf(v.x); b.y = f2bf(v.y); b.z = f2bf(v.z); b.w = f2bf(v.w);
    reinterpret_cast<ushort4*>(Fb + (size_t)row * D_K)[lane] = b;
    // fp32 squared norm
    float s = v.x * v.x + v.y * v.y + v.z * v.z + v.w * v.w;
#pragma unroll
    for (int off = 32; off > 0; off >>= 1) s += __shfl_down(s, off);
    if (lane == 0) {
        sq[row] = s;
        const int* lp = labels + (size_t)row * 3;
        plab[row] = lp[0] | (lp[1] << 3) | (lp[2] << 6);
    }
}

// ---------------------------------------------------------------------------
// pair: one wave per 64x64 upper-triangular gram tile.
// 4x4 grid of mfma_f32_16x16x32_bf16; A and B frags loaded straight from
// global (both operands are rows of F since Gram = F . F^T):
//   A[m][k]: m = lane&15, k = (lane>>4)*8 + j   (16B contiguous per lane)
//   B[k][n]: n = lane&15, same k pattern        (identical load shape)
//   C/D   : col = lane&15, row = (lane>>4)*4 + reg   [verified m89]
// ---------------------------------------------------------------------------
__global__ __launch_bounds__(64) void pair_kernel(const unsigned short* __restrict__ Fb,
                                                  const float* __restrict__ sq,
                                                  const int* __restrict__ plab,
                                                  float* __restrict__ out) {
    int idx = blockIdx.x;
    int bi = 0;
    while (idx >= NT - bi) { idx -= NT - bi; ++bi; }
    int bj = bi + idx;

    const int i0 = bi * TILE;
    const int j0 = bj * TILE;
    const int lane = threadIdx.x;
    const int lrow = lane & 15;
    const int kgrp = lane >> 4;     // 0..3

    floatx4 zero = {0.f, 0.f, 0.f, 0.f};
    floatx4 acc[4][4];
#pragma unroll
    for (int tm = 0; tm < 4; ++tm)
#pragma unroll
        for (int tn = 0; tn < 4; ++tn) acc[tm][tn] = zero;

    for (int k0 = 0; k0 < D_K; k0 += 32) {
        bf16x8 a[4], b[4];
#pragma unroll
        for (int tm = 0; tm < 4; ++tm) {
            size_t row = (size_t)(i0 + tm * 16 + lrow);
            a[tm] = *reinterpret_cast<const bf16x8*>(Fb + row * D_K + k0 + kgrp * 8);
        }
#pragma unroll
        for (int tn = 0; tn < 4; ++tn) {
            size_t row = (size_t)(j0 + tn * 16 + lrow);
            b[tn] = *reinterpret_cast<const bf16x8*>(Fb + row * D_K + k0 + kgrp * 8);
        }
#pragma unroll
        for (int tm = 0; tm < 4; ++tm)
#pragma unroll
            for (int tn = 0; tn < 4; ++tn)
                acc[tm][tn] = __builtin_amdgcn_mfma_f32_16x16x32_bf16(a[tm], b[tn], acc[tm][tn], 0, 0, 0);
    }

    // epilogue: d2 = sq_i + sq_j - 2g, contrastive term, j>i mask
    float sqj[4];
    int   lj[4];
#pragma unroll
    for (int tn = 0; tn < 4; ++tn) {
        int j = j0 + tn * 16 + lrow;
        sqj[tn] = sq[j];
        lj[tn]  = plab[j];
    }

    float local = 0.f;
#pragma unroll
    for (int tm = 0; tm < 4; ++tm) {
#pragma unroll
        for (int r = 0; r < 4; ++r) {
            int i = i0 + tm * 16 + kgrp * 4 + r;
            float sqi = sq[i];
            int   li  = plab[i];
#pragma unroll
            for (int tn = 0; tn < 4; ++tn) {
                int j = j0 + tn * 16 + lrow;
                if (j > i) {
                    float g  = acc[tm][tn][r];
                    float d2 = fmaxf(sqi + sqj[tn] - 2.f * g, 0.f);
                    float dist = sqrtf(d2);
                    local += (li == lj[tn]) ? (0.5f * dist)
                                            : (0.5f * fmaxf(1.f - dist, 0.f));
                }
            }
        }
    }

#pragma unroll
    for (int off = 32; off > 0; off >>= 1) local += __shfl_down(local, off);
    if (lane == 0) atomicAdd(out, local * (1.0f / B_N));
}

extern "C" void kernel_launch(void* const* d_in, const int* in_sizes, int n_in,
                              void* d_out, int out_size, void* d_ws, size_t ws_size,
                              hipStream_t stream) {
    const float* F      = (const float*)d_in[0];
    const int*   labels = (const int*)d_in[1];
    float* out = (float*)d_out;

    float*          sq   = (float*)d_ws;                                    // 16 KB
    int*            plab = (int*)((char*)d_ws + B_N * sizeof(float));       // 16 KB
    unsigned short* Fb   = (unsigned short*)((char*)d_ws + 2 * B_N * 4);    // 2 MB bf16

    hipMemsetAsync(out, 0, sizeof(float), stream);
    prep_kernel<<<B_N / 4, 256, 0, stream>>>(F, labels, sq, plab, Fb);
    pair_kernel<<<NT * (NT + 1) / 2, 64, 0, stream>>>(Fb, sq, plab, out);
}

// Round 3
// 90.975 us; speedup vs baseline: 1.6711x; 1.2004x over previous
//
#include <hip/hip_runtime.h>

#define B_N 4096
#define D_K 256
#define TILE 64
#define NT (B_N / TILE)                 // 64 tiles/dim
#define NTILES (NT * (NT + 1) / 2)      // 2080 triangular tiles
#define NBLOCKS (NTILES / 4)            // 520 blocks, 4 waves each

typedef __bf16 bf16x8 __attribute__((ext_vector_type(8)));
typedef float  floatx4 __attribute__((ext_vector_type(4)));

__device__ inline unsigned short f2bf(float f) {
    unsigned int u = __float_as_uint(f);
    return (unsigned short)((u + 0x7FFFu + ((u >> 16) & 1u)) >> 16);
}

// ---------------------------------------------------------------------------
// prep: fp32 squared norms (exact), packed labels, bf16 copy of F.
// ---------------------------------------------------------------------------
__global__ __launch_bounds__(256) void prep_kernel(const float* __restrict__ F,
                                                   const int* __restrict__ labels,
                                                   float* __restrict__ sq,
                                                   int* __restrict__ plab,
                                                   unsigned short* __restrict__ Fb) {
    int row  = blockIdx.x * 4 + (threadIdx.x >> 6);
    int lane = threadIdx.x & 63;
    const float4* fp = reinterpret_cast<const float4*>(F + (size_t)row * D_K);
    float4 v = fp[lane];
    ushort4 b;
    b.x = f2bf(v.x); b.y = f2bf(v.y); b.z = f2bf(v.z); b.w = f2bf(v.w);
    reinterpret_cast<ushort4*>(Fb + (size_t)row * D_K)[lane] = b;
    float s = v.x * v.x + v.y * v.y + v.z * v.z + v.w * v.w;
#pragma unroll
    for (int off = 32; off > 0; off >>= 1) s += __shfl_down(s, off);
    if (lane == 0) {
        sq[row] = s;
        const int* lp = labels + (size_t)row * 3;
        plab[row] = lp[0] | (lp[1] << 3) | (lp[2] << 6);
    }
}

// ---------------------------------------------------------------------------
// pair: 4 waves/block, one 64x64 triangular gram tile per wave.
// mfma_f32_16x16x32_bf16, frags straight from global (L1/L2-resident),
// k-loop software-pipelined. NO atomics: per-block partial -> partials[].
// ---------------------------------------------------------------------------
__global__ __launch_bounds__(256) void pair_kernel(const unsigned short* __restrict__ Fb,
                                                   const float* __restrict__ sq,
                                                   const int* __restrict__ plab,
                                                   float* __restrict__ partials) {
    __shared__ float red[4];
    int tile = blockIdx.x * 4 + (threadIdx.x >> 6);
    int lane = threadIdx.x & 63;

    int idx = tile, bi = 0;
    while (idx >= NT - bi) { idx -= NT - bi; ++bi; }
    int bj = bi + idx;

    const int i0 = bi * TILE;
    const int j0 = bj * TILE;
    const int lrow = lane & 15;
    const int kgrp = lane >> 4;     // 0..3

    floatx4 acc[4][4];
#pragma unroll
    for (int tm = 0; tm < 4; ++tm)
#pragma unroll
        for (int tn = 0; tn < 4; ++tn) acc[tm][tn] = floatx4{0.f, 0.f, 0.f, 0.f};

    const unsigned short* Arow = Fb + (size_t)(i0 + lrow) * D_K + kgrp * 8;
    const unsigned short* Brow = Fb + (size_t)(j0 + lrow) * D_K + kgrp * 8;

    bf16x8 a[4], b[4], a2[4], b2[4];
#pragma unroll
    for (int tm = 0; tm < 4; ++tm) {
        a[tm] = *reinterpret_cast<const bf16x8*>(Arow + tm * 16 * D_K);
        b[tm] = *reinterpret_cast<const bf16x8*>(Brow + tm * 16 * D_K);
    }

    for (int k0 = 0; k0 < D_K; k0 += 32) {
        if (k0 + 32 < D_K) {
#pragma unroll
            for (int tm = 0; tm < 4; ++tm) {
                a2[tm] = *reinterpret_cast<const bf16x8*>(Arow + tm * 16 * D_K + k0 + 32);
                b2[tm] = *reinterpret_cast<const bf16x8*>(Brow + tm * 16 * D_K + k0 + 32);
            }
        }
#pragma unroll
        for (int tm = 0; tm < 4; ++tm)
#pragma unroll
            for (int tn = 0; tn < 4; ++tn)
                acc[tm][tn] = __builtin_amdgcn_mfma_f32_16x16x32_bf16(a[tm], b[tn], acc[tm][tn], 0, 0, 0);
#pragma unroll
        for (int tm = 0; tm < 4; ++tm) { a[tm] = a2[tm]; b[tm] = b2[tm]; }
    }

    // epilogue: d2 = sq_i + sq_j - 2g; contrastive term; strict j>i mask
    float sqj[4];
    int   lj[4];
#pragma unroll
    for (int tn = 0; tn < 4; ++tn) {
        int j = j0 + tn * 16 + lrow;
        sqj[tn] = sq[j];
        lj[tn]  = plab[j];
    }

    float local = 0.f;
#pragma unroll
    for (int tm = 0; tm < 4; ++tm) {
#pragma unroll
        for (int r = 0; r < 4; ++r) {
            int i = i0 + tm * 16 + kgrp * 4 + r;
            float sqi = sq[i];
            int   li  = plab[i];
#pragma unroll
            for (int tn = 0; tn < 4; ++tn) {
                int j = j0 + tn * 16 + lrow;
                if (j > i) {
                    float d2 = fmaxf(sqi + sqj[tn] - 2.f * acc[tm][tn][r], 0.f);
                    float dist = sqrtf(d2);
                    local += (li == lj[tn]) ? (0.5f * dist)
                                            : (0.5f * fmaxf(1.f - dist, 0.f));
                }
            }
        }
    }

#pragma unroll
    for (int off = 32; off > 0; off >>= 1) local += __shfl_down(local, off);
    if (lane == 0) red[threadIdx.x >> 6] = local;
    __syncthreads();
    if (threadIdx.x == 0)
        partials[blockIdx.x] = red[0] + red[1] + red[2] + red[3];
}

// ---------------------------------------------------------------------------
// reduce: 520 partials -> out[0], single block (no atomics, no memset needed)
// ---------------------------------------------------------------------------
__global__ __launch_bounds__(256) void reduce_kernel(const float* __restrict__ partials,
                                                     float* __restrict__ out) {
    __shared__ float red[4];
    float s = 0.f;
    for (int i = threadIdx.x; i < NBLOCKS; i += 256) s += partials[i];
#pragma unroll
    for (int off = 32; off > 0; off >>= 1) s += __shfl_down(s, off);
    if ((threadIdx.x & 63) == 0) red[threadIdx.x >> 6] = s;
    __syncthreads();
    if (threadIdx.x == 0)
        out[0] = (red[0] + red[1] + red[2] + red[3]) * (1.0f / B_N);
}

extern "C" void kernel_launch(void* const* d_in, const int* in_sizes, int n_in,
                              void* d_out, int out_size, void* d_ws, size_t ws_size,
                              hipStream_t stream) {
    const float* F      = (const float*)d_in[0];
    const int*   labels = (const int*)d_in[1];
    float* out = (float*)d_out;

    float*          sq    = (float*)d_ws;                                   // 16 KB
    int*            plab  = (int*)((char*)d_ws + B_N * 4);                  // 16 KB
    float*          parts = (float*)((char*)d_ws + 2 * B_N * 4);            // 2080 B
    unsigned short* Fb    = (unsigned short*)((char*)d_ws + 3 * B_N * 4);   // 2 MB

    prep_kernel<<<B_N / 4, 256, 0, stream>>>(F, labels, sq, plab, Fb);
    pair_kernel<<<NBLOCKS, 256, 0, stream>>>(Fb, sq, plab, parts);
    reduce_kernel<<<1, 256, 0, stream>>>(parts, out);
}

// Round 4
// 76.757 us; speedup vs baseline: 1.9807x; 1.1852x over previous
//
#include <hip/hip_runtime.h>

#define B_N 4096
#define D_K 256
#define BT  128                     // block tile (128x128)
#define NT  (B_N / BT)              // 32
#define NBLK (NT * (NT + 1) / 2)    // 528 triangular blocks
#define BK  64                      // k-chunk
#define NKITER (D_K / BK)           // 4

typedef __bf16 bf16x8 __attribute__((ext_vector_type(8)));
typedef float  floatx4 __attribute__((ext_vector_type(4)));

typedef __attribute__((address_space(3))) unsigned int lds_u32;
typedef const __attribute__((address_space(1))) unsigned int glb_u32;

__device__ inline unsigned short f2bf(float f) {
    unsigned int u = __float_as_uint(f);
    return (unsigned short)((u + 0x7FFFu + ((u >> 16) & 1u)) >> 16);
}

// ---------------------------------------------------------------------------
// prep: fp32 squared norms (exact), packed labels, bf16 copy of F.
// ---------------------------------------------------------------------------
__global__ __launch_bounds__(256) void prep_kernel(const float* __restrict__ F,
                                                   const int* __restrict__ labels,
                                                   float* __restrict__ sq,
                                                   int* __restrict__ plab,
                                                   unsigned short* __restrict__ Fb) {
    int row  = blockIdx.x * 4 + (threadIdx.x >> 6);
    int lane = threadIdx.x & 63;
    const float4* fp = reinterpret_cast<const float4*>(F + (size_t)row * D_K);
    float4 v = fp[lane];
    ushort4 b;
    b.x = f2bf(v.x); b.y = f2bf(v.y); b.z = f2bf(v.z); b.w = f2bf(v.w);
    reinterpret_cast<ushort4*>(Fb + (size_t)row * D_K)[lane] = b;
    float s = v.x * v.x + v.y * v.y + v.z * v.z + v.w * v.w;
#pragma unroll
    for (int off = 32; off > 0; off >>= 1) s += __shfl_down(s, off);
    if (lane == 0) {
        sq[row] = s;
        const int* lp = labels + (size_t)row * 3;
        plab[row] = lp[0] | (lp[1] << 3) | (lp[2] << 6);
    }
}

// ---------------------------------------------------------------------------
// pair: m97-style. 128x128 gram tile / block (4 waves, 64x64 quadrant each).
// Staging: global_load_lds width-16, XOR-swizzled chunk layout:
//   LDS byte offset of (row, chunk) = row*128 + ((chunk ^ (row&7)) * 16)
// -> staging stays 64B-coalesced, frag ds_read_b128 is 2-way max (free).
// MFMA: 4x4 grid of 16x16x32_bf16 per wave; C/D: col=lane&15, row=quad*4+reg.
// ---------------------------------------------------------------------------
__global__ __launch_bounds__(256) void pair_kernel(const unsigned short* __restrict__ Fb,
                                                   const float* __restrict__ sq,
                                                   const int* __restrict__ plab,
                                                   float* __restrict__ partials) {
    __shared__ unsigned short As[BT * BK];   // 16 KB
    __shared__ unsigned short Bs[BT * BK];   // 16 KB
    __shared__ float red[4];

    // triangular decode: (bi, bj), bi <= bj
    int idx = blockIdx.x, bi = 0;
    while (idx >= NT - bi) { idx -= NT - bi; ++bi; }
    int bj = bi + idx;

    const int i0   = bi * BT;
    const int j0   = bj * BT;
    const int wave = threadIdx.x >> 6;
    const int lane = threadIdx.x & 63;
    const int lrow = lane & 15;
    const int kgrp = lane >> 4;          // 0..3
    const int wy   = wave >> 1;          // quadrant row
    const int wx   = wave & 1;           // quadrant col
    const int r0   = wy * 64;
    const int c0   = wx * 64;

    floatx4 acc[4][4];
#pragma unroll
    for (int tm = 0; tm < 4; ++tm)
#pragma unroll
        for (int tn = 0; tn < 4; ++tn) acc[tm][tn] = floatx4{0.f, 0.f, 0.f, 0.f};

    // staging geometry: 8 chunks of 16B per row (BK=64 bf16 = 128 B/row)
    // instr q covers rows q*8..q*8+7; lane: row = q*8 + lane/8, phys = lane%8,
    // logical chunk = phys ^ (row&7)
    const int srow_in = (lane >> 3);               // 0..7 within instr
    const int sphys   = lane & 7;

    const char* gA = (const char*)(Fb + (size_t)i0 * D_K);
    const char* gB = (const char*)(Fb + (size_t)j0 * D_K);
    char* lAs = (char*)As;
    char* lBs = (char*)Bs;

    for (int it = 0; it < NKITER; ++it) {
        const size_t kbyte = (size_t)it * BK * 2;
        // each wave stages 4 A-instrs + 4 B-instrs (16+16 total per block)
#pragma unroll
        for (int q = 0; q < 4; ++q) {
            int instr = wave * 4 + q;              // 0..15
            int row   = instr * 8 + srow_in;       // 0..127
            int chunk = sphys ^ (row & 7);
            __builtin_amdgcn_global_load_lds(
                (glb_u32*)(gA + (size_t)row * (D_K * 2) + kbyte + chunk * 16),
                (lds_u32*)(lAs + instr * 1024), 16, 0, 0);
            __builtin_amdgcn_global_load_lds(
                (glb_u32*)(gB + (size_t)row * (D_K * 2) + kbyte + chunk * 16),
                (lds_u32*)(lBs + instr * 1024), 16, 0, 0);
        }
        __syncthreads();   // drains vmcnt (compiler emits waitcnt before barrier)

#pragma unroll
        for (int ks = 0; ks < 2; ++ks) {
            bf16x8 a[4], b[4];
            const int chunk = ks * 4 + kgrp;       // 0..7
#pragma unroll
            for (int tm = 0; tm < 4; ++tm) {
                int row = r0 + tm * 16 + lrow;
                a[tm] = *reinterpret_cast<const bf16x8*>(
                    (const char*)As + row * 128 + ((chunk ^ (row & 7)) * 16));
            }
#pragma unroll
            for (int tn = 0; tn < 4; ++tn) {
                int row = c0 + tn * 16 + lrow;
                b[tn] = *reinterpret_cast<const bf16x8*>(
                    (const char*)Bs + row * 128 + ((chunk ^ (row & 7)) * 16));
            }
#pragma unroll
            for (int tm = 0; tm < 4; ++tm)
#pragma unroll
                for (int tn = 0; tn < 4; ++tn)
                    acc[tm][tn] = __builtin_amdgcn_mfma_f32_16x16x32_bf16(
                        a[tm], b[tn], acc[tm][tn], 0, 0, 0);
        }
        __syncthreads();   // before next iter overwrites As/Bs
    }

    // epilogue: d2 = sq_i + sq_j - 2g; contrastive term; strict j>i mask
    float sqj[4];
    int   lj[4];
#pragma unroll
    for (int tn = 0; tn < 4; ++tn) {
        int j = j0 + c0 + tn * 16 + lrow;
        sqj[tn] = sq[j];
        lj[tn]  = plab[j];
    }

    float local = 0.f;
#pragma unroll
    for (int tm = 0; tm < 4; ++tm) {
#pragma unroll
        for (int r = 0; r < 4; ++r) {
            int i = i0 + r0 + tm * 16 + kgrp * 4 + r;
            float sqi = sq[i];
            int   li  = plab[i];
#pragma unroll
            for (int tn = 0; tn < 4; ++tn) {
                int j = j0 + c0 + tn * 16 + lrow;
                if (j > i) {
                    float d2 = fmaxf(sqi + sqj[tn] - 2.f * acc[tm][tn][r], 0.f);
                    float dist = sqrtf(d2);
                    local += (li == lj[tn]) ? (0.5f * dist)
                                            : (0.5f * fmaxf(1.f - dist, 0.f));
                }
            }
        }
    }

#pragma unroll
    for (int off = 32; off > 0; off >>= 1) local += __shfl_down(local, off);
    if (lane == 0) red[wave] = local;
    __syncthreads();
    if (threadIdx.x == 0)
        partials[blockIdx.x] = red[0] + red[1] + red[2] + red[3];
}

// ---------------------------------------------------------------------------
// reduce: 528 partials -> out[0]
// ---------------------------------------------------------------------------
__global__ __launch_bounds__(256) void reduce_kernel(const float* __restrict__ partials,
                                                     float* __restrict__ out) {
    __shared__ float red[4];
    float s = 0.f;
    for (int i = threadIdx.x; i < NBLK; i += 256) s += partials[i];
#pragma unroll
    for (int off = 32; off > 0; off >>= 1) s += __shfl_down(s, off);
    if ((threadIdx.x & 63) == 0) red[threadIdx.x >> 6] = s;
    __syncthreads();
    if (threadIdx.x == 0)
        out[0] = (red[0] + red[1] + red[2] + red[3]) * (1.0f / B_N);
}

extern "C" void kernel_launch(void* const* d_in, const int* in_sizes, int n_in,
                              void* d_out, int out_size, void* d_ws, size_t ws_size,
                              hipStream_t stream) {
    const float* F      = (const float*)d_in[0];
    const int*   labels = (const int*)d_in[1];
    float* out = (float*)d_out;

    float*          sq    = (float*)d_ws;                                   // 16 KB
    int*            plab  = (int*)((char*)d_ws + B_N * 4);                  // 16 KB
    float*          parts = (float*)((char*)d_ws + 2 * B_N * 4);            // ~2 KB
    unsigned short* Fb    = (unsigned short*)((char*)d_ws + 3 * B_N * 4);   // 2 MB

    prep_kernel<<<B_N / 4, 256, 0, stream>>>(F, labels, sq, plab, Fb);
    pair_kernel<<<NBLK, 256, 0, stream>>>(Fb, sq, plab, parts);
    reduce_kernel<<<1, 256, 0, stream>>>(parts, out);
}